// Round 1
// baseline (387.486 us; speedup 1.0000x reference)
//
#include <hip/hip_runtime.h>
#include <cstdint>
#include <cstddef>

// Problem dims
#define B_ROWS 65536
#define D_IN   784
#define KP     800      // D_IN padded to multiple of 32
#define D_H    300
#define NP     320      // D_H padded to multiple of 64
#define D_OUT  10
#define NP2    16       // D_OUT padded to 16
#define EPS    1e-5f

typedef _Float16 half8  __attribute__((ext_vector_type(8)));
typedef float    floatx4 __attribute__((ext_vector_type(4)));

// Workspace layout (bytes), all offsets 256-aligned. Total ~46.7 MB.
#define OFF_S1   ((size_t)0)                       // _Float16[320*800]   = 512000
#define OFF_H    ((size_t)512000)                  // _Float16[65536*320] = 41943040
#define OFF_ST1  (OFF_H + (size_t)41943040)        // float[640] sum+sumsq
#define OFF_W2   (OFF_ST1 + (size_t)2560)          // _Float16[16*320]    = 10240
#define OFF_ST2  (OFF_W2 + (size_t)10240)          // float[32] sum+sumsq
#define OFF_OC   (OFF_ST2 + (size_t)256)           // float[65536*16]     = 4194304

// ---------------- K0: binarize W1 -> fp16 (+-1), zero-padded to [320][800]
__global__ void k_prep1(const float* __restrict__ W1, _Float16* __restrict__ S1)
{
    int idx = blockIdx.x * 256 + threadIdx.x;      // 0..255999
    int n = idx / KP;
    int k = idx - n * KP;
    float v = 0.0f;
    if (n < D_H && k < D_IN)
        v = (W1[n * D_IN + k] >= 0.0f) ? 1.0f : -1.0f;
    S1[idx] = (_Float16)v;
}

// ---------------- K1: h = x @ S1^T  (M=65536, N=320, K=800), fp16 MFMA
// Block: 256 thr (4 waves), tile 64 rows x 320 cols (full N -> x read once).
// Wave w: rows 0..63 x cols [w*80, w*80+80) -> acc 4x5 tiles of 16x16.
__global__ __launch_bounds__(256, 3) void k_gemm1(const float* __restrict__ x,
                                                  const _Float16* __restrict__ S1,
                                                  _Float16* __restrict__ h)
{
    __shared__ _Float16 Alds[64][32];    // 4 KB
    __shared__ _Float16 Blds[NP][32];    // 20 KB
    const int t     = threadIdx.x;
    const int wave  = t >> 6;
    const int lane  = t & 63;
    const int row15 = lane & 15;
    const int quad  = lane >> 4;
    const int m0    = blockIdx.x * 64;

    floatx4 acc[4][5] = {};

    const int ar = t >> 2;          // 0..63 : A-stage row
    const int ac = (t & 3) * 8;     // 0,8,16,24 : A-stage col (8 floats)
    const float* xp = x + (size_t)(m0 + ar) * D_IN + ac;

    for (int kk = 0; kk < KP; kk += 32) {
        __syncthreads();
        // --- stage A (fp32 -> fp16), zero-pad k >= 784 (784 % 8 == 0)
        {
            floatx4 v0 = {}, v1 = {};
            int k = kk + ac;
            if (k < D_IN) {
                v0 = *(const floatx4*)(xp + kk);
                v1 = *(const floatx4*)(xp + kk + 4);
            }
            half8 hv;
#pragma unroll
            for (int i = 0; i < 4; ++i) { hv[i] = (_Float16)v0[i]; hv[4 + i] = (_Float16)v1[i]; }
            *(half8*)&Alds[ar][ac] = hv;
        }
        // --- stage B: 320x32 fp16 = 1280 16B-chunks, 5 per thread
#pragma unroll
        for (int i = 0; i < 5; ++i) {
            int c  = i * 256 + t;       // 0..1279
            int br = c >> 2;            // row 0..319
            int bc = (c & 3) * 8;       // 0,8,16,24
            *(half8*)&Blds[br][bc] = *(const half8*)(S1 + (size_t)br * KP + kk + bc);
        }
        __syncthreads();
        // --- compute
        half8 a[4];
#pragma unroll
        for (int mt = 0; mt < 4; ++mt)
            a[mt] = *(const half8*)&Alds[mt * 16 + row15][quad * 8];
#pragma unroll
        for (int nt = 0; nt < 5; ++nt) {
            half8 b = *(const half8*)&Blds[wave * 80 + nt * 16 + row15][quad * 8];
#pragma unroll
            for (int mt = 0; mt < 4; ++mt)
                acc[mt][nt] = __builtin_amdgcn_mfma_f32_16x16x32_f16(a[mt], b, acc[mt][nt], 0, 0, 0);
        }
    }
    // --- epilogue: C/D layout col=lane&15, row=quad*4+r
#pragma unroll
    for (int mt = 0; mt < 4; ++mt)
#pragma unroll
        for (int nt = 0; nt < 5; ++nt)
#pragma unroll
            for (int r = 0; r < 4; ++r) {
                int m = m0 + mt * 16 + quad * 4 + r;
                int n = wave * 80 + nt * 16 + row15;
                h[(size_t)m * NP + n] = (_Float16)acc[mt][nt][r];
            }
}

// ---------------- K2: per-column sum / sumsq of h over 65536 rows
__global__ void k_stats1(const _Float16* __restrict__ h, float* __restrict__ st)
{
    int t = threadIdx.x;                 // 320 threads = 1 column each
    const _Float16* p = h + (size_t)blockIdx.x * 128 * NP + t;
    float s = 0.f, q = 0.f;
    for (int r = 0; r < 128; ++r) {
        float v = (float)p[(size_t)r * NP];
        s += v; q += v * v;
    }
    atomicAdd(&st[t], s);
    atomicAdd(&st[NP + t], q);
}

// ---------------- K3: fold BN1 scale into binarized W2 -> w2h[16][320] fp16
__global__ void k_prep2(const float* __restrict__ st, const float* __restrict__ gamma1,
                        const float* __restrict__ W2, _Float16* __restrict__ w2h)
{
    int j = threadIdx.x;                 // 0..319
    float mean = st[j] * (1.0f / 65536.0f);
    float var  = st[NP + j] * (1.0f / 65536.0f) - mean * mean;
    float a1   = 0.0f;
    if (j < D_H) a1 = gamma1[j] / sqrtf(var + EPS);
    for (int k = 0; k < NP2; ++k) {
        float w = 0.0f;
        if (k < D_OUT && j < D_H)
            w = (W2[k * D_H + j] >= 0.0f) ? a1 : -a1;
        w2h[k * NP + j] = (_Float16)w;
    }
}

// ---------------- K4: oc = h @ w2h^T  (K=320, N=16) + fused column stats of oc
__global__ __launch_bounds__(256) void k_gemm2(const _Float16* __restrict__ h,
                                               const _Float16* __restrict__ w2h,
                                               float* __restrict__ oc,
                                               float* __restrict__ st2)
{
    __shared__ _Float16 Wlds[16][328];   // pad 320->328 to break 16-way bank conflict
    __shared__ float reds[4][16], redq[4][16];
    const int t     = threadIdx.x;
    const int wave  = t >> 6;
    const int lane  = t & 63;
    const int row15 = lane & 15;
    const int quad  = lane >> 4;

    for (int c = t; c < 640; c += 256) { // 16*320/8 chunks
        int r  = c / 40;
        int cc = (c - r * 40) * 8;
        *(half8*)&Wlds[r][cc] = *(const half8*)(w2h + r * NP + cc);
    }
    __syncthreads();

    const int m0 = blockIdx.x * 64 + wave * 16;
    const _Float16* hp = h + (size_t)(m0 + row15) * NP + quad * 8;
    floatx4 acc = {};
#pragma unroll
    for (int kk = 0; kk < NP; kk += 32) {
        half8 a = *(const half8*)(hp + kk);
        half8 b = *(const half8*)&Wlds[row15][kk + quad * 8];
        acc = __builtin_amdgcn_mfma_f32_16x16x32_f16(a, b, acc, 0, 0, 0);
    }
    float s = 0.f, q = 0.f;
#pragma unroll
    for (int r = 0; r < 4; ++r) {
        float v = acc[r];
        oc[(size_t)(m0 + quad * 4 + r) * NP2 + row15] = v;
        s += v; q += v * v;
    }
    // reduce over the 4 quad-groups (rows) -> lanes 0..15 hold column totals
    s += __shfl_xor(s, 16); s += __shfl_xor(s, 32);
    q += __shfl_xor(q, 16); q += __shfl_xor(q, 32);
    if (lane < 16) { reds[wave][row15] = s; redq[wave][row15] = q; }
    __syncthreads();
    if (t < 16) {
        float S = reds[0][t] + reds[1][t] + reds[2][t] + reds[3][t];
        float Q = redq[0][t] + redq[1][t] + redq[2][t] + redq[3][t];
        atomicAdd(&st2[t], S);
        atomicAdd(&st2[16 + t], Q);
    }
}

// ---------------- K5: BN2 epilogue -> out[65536][10] fp32
__global__ void k_final(const float* __restrict__ oc, const float* __restrict__ st2,
                        const float* __restrict__ gamma2, const float* __restrict__ beta2,
                        float* __restrict__ out)
{
    int idx = blockIdx.x * 256 + threadIdx.x;    // 2560*256 == 655360 exactly
    int m = idx / 10;
    int k = idx - m * 10;
    float mean = st2[k] * (1.0f / 65536.0f);
    float var  = st2[16 + k] * (1.0f / 65536.0f) - mean * mean;
    float sc   = gamma2[k] / sqrtf(var + EPS);
    out[idx] = (oc[(size_t)m * NP2 + k] - mean) * sc + beta2[k];
}

extern "C" void kernel_launch(void* const* d_in, const int* in_sizes, int n_in,
                              void* d_out, int out_size, void* d_ws, size_t ws_size,
                              hipStream_t stream)
{
    const float* x      = (const float*)d_in[0];
    const float* W1     = (const float*)d_in[1];
    const float* gamma1 = (const float*)d_in[2];
    // d_in[3] = beta1 : algebraically cancels under BN2's mean subtraction
    const float* W2     = (const float*)d_in[4];
    const float* gamma2 = (const float*)d_in[5];
    const float* beta2  = (const float*)d_in[6];
    float* out = (float*)d_out;

    char* ws = (char*)d_ws;
    _Float16* S1  = (_Float16*)(ws + OFF_S1);
    _Float16* h   = (_Float16*)(ws + OFF_H);
    float*    st1 = (float*)(ws + OFF_ST1);
    _Float16* w2h = (_Float16*)(ws + OFF_W2);
    float*    st2 = (float*)(ws + OFF_ST2);
    float*    oc  = (float*)(ws + OFF_OC);

    hipMemsetAsync(st1, 0, 640 * sizeof(float), stream);
    hipMemsetAsync(st2, 0, 32 * sizeof(float), stream);

    k_prep1 <<<1000, 256, 0, stream>>>(W1, S1);
    k_gemm1 <<<1024, 256, 0, stream>>>(x, S1, h);
    k_stats1<<<512, 320, 0, stream>>>(h, st1);
    k_prep2 <<<1, 320, 0, stream>>>(st1, gamma1, W2, w2h);
    k_gemm2 <<<1024, 256, 0, stream>>>(h, w2h, oc, st2);
    k_final <<<2560, 256, 0, stream>>>(oc, st2, gamma2, beta2, out);
}